// Round 5
// baseline (419.186 us; speedup 1.0000x reference)
//
#include <hip/hip_runtime.h>
#include <hip/hip_bf16.h>

// B=2, S=2048, D=1024, H=16, DH=64. f32 in/out; bf16 intermediates for MFMA.
#define Bn 2
#define Sn 2048
#define Dn 1024
#define Hn 16
#define DHn 64
#define Kd 1024
#define Mn (Bn * Sn)
#define LN10K 9.210340371976184f

typedef __attribute__((ext_vector_type(8))) short bf16x8;  // MFMA A/B frag
typedef __attribute__((ext_vector_type(4))) float f32x4;   // MFMA C/D frag

static __device__ __forceinline__ ushort f2bf(float f) {
    uint u = __float_as_uint(f);
    u += 0x7fff + ((u >> 16) & 1);   // round-nearest-even
    return (ushort)(u >> 16);
}

#define MFMA16(a, b, c) __builtin_amdgcn_mfma_f32_16x16x32_bf16((a), (b), (c), 0, 0, 0)

// ---------------------------------------------------------------------------
// RoPE table: ctab/stab[s][fe], s in [0,2048), fe in [0,32).
// ---------------------------------------------------------------------------
__global__ __launch_bounds__(256) void rope_tab(float* __restrict__ ct,
                                                float* __restrict__ st)
{
    const int idx = blockIdx.x * 256 + threadIdx.x;
    const int s = idx >> 5, fe = idx & 31;
    const float f = expf(-LN10K * (float)fe / 32.0f);
    const float a = (float)s * f;
    ct[idx] = cosf(a);
    st[idx] = sinf(a);
}

// ---------------------------------------------------------------------------
// f32 -> bf16 elementwise (8 per thread).
// ---------------------------------------------------------------------------
__global__ __launch_bounds__(256) void cvt_bf16(const float* __restrict__ in,
                                                ushort* __restrict__ out)
{
    const size_t i = ((size_t)blockIdx.x * 256 + threadIdx.x) * 8;
    const float4 a = *(const float4*)(in + i);
    const float4 b = *(const float4*)(in + i + 4);
    ushort4 lo = make_ushort4(f2bf(a.x), f2bf(a.y), f2bf(a.z), f2bf(a.w));
    ushort4 hi = make_ushort4(f2bf(b.x), f2bf(b.y), f2bf(b.z), f2bf(b.w));
    *(ushort4*)(out + i) = lo;
    *(ushort4*)(out + i + 4) = hi;
}

// ---------------------------------------------------------------------------
// Transpose + convert: in f32 [R][C] -> out bf16 [C][R]. 32x32 tiles.
// ---------------------------------------------------------------------------
__global__ __launch_bounds__(256) void transpose_bf16(
    const float* __restrict__ in, ushort* __restrict__ out, int R, int C)
{
    __shared__ ushort t[32][33];
    const int n0 = blockIdx.x * 32, k0 = blockIdx.y * 32;
    const int x = threadIdx.x, y = threadIdx.y;
#pragma unroll
    for (int i = 0; i < 4; ++i)
        t[y + 8 * i][x] = f2bf(in[(size_t)(k0 + y + 8 * i) * C + n0 + x]);
    __syncthreads();
#pragma unroll
    for (int i = 0; i < 4; ++i)
        out[(size_t)(n0 + y + 8 * i) * R + k0 + x] = t[x][y + 8 * i];
}

// ---------------------------------------------------------------------------
// MFMA GEMM, LDS-free (as round 4).
// ---------------------------------------------------------------------------
template <int MODE>
__global__ __launch_bounds__(256) void gemm_mfma(
    const ushort* __restrict__ A, const ushort* __restrict__ Bt,
    const float* __restrict__ bias, const float* __restrict__ ctab,
    const float* __restrict__ stab, ushort* __restrict__ o0,
    ushort* __restrict__ o1)
{
    const int tid = threadIdx.x;
    const int lane = tid & 63, w = tid >> 6;
    const int g = lane >> 4, c = lane & 15;
    const int mbase = blockIdx.y * 128 + (w >> 1) * 64;
    const int nbase = blockIdx.x * 128 + (w & 1) * 64;

    f32x4 acc[4][4];
#pragma unroll
    for (int mf = 0; mf < 4; ++mf)
#pragma unroll
        for (int nf = 0; nf < 4; ++nf)
            acc[mf][nf] = (f32x4){0.f, 0.f, 0.f, 0.f};

    const ushort* Ap = A + (size_t)(mbase + c) * Kd + g * 8;
    const ushort* Bp = Bt + (size_t)(nbase + c) * Kd + g * 8;

    for (int k0 = 0; k0 < Kd; k0 += 32) {
        bf16x8 af[4], bfr[4];
#pragma unroll
        for (int mf = 0; mf < 4; ++mf)
            af[mf] = *(const bf16x8*)(Ap + (size_t)mf * 16 * Kd + k0);
#pragma unroll
        for (int nf = 0; nf < 4; ++nf)
            bfr[nf] = *(const bf16x8*)(Bp + (size_t)nf * 16 * Kd + k0);
#pragma unroll
        for (int mf = 0; mf < 4; ++mf)
#pragma unroll
            for (int nf = 0; nf < 4; ++nf)
                acc[mf][nf] = MFMA16(af[mf], bfr[nf], acc[mf][nf]);
    }

#pragma unroll
    for (int nf = 0; nf < 4; ++nf) {
        const int col = nbase + nf * 16 + c;
        const float bs = bias[col];
        if (MODE == 0) {
            const int dh = col & 63, h = (col >> 6) & 15, isK = col >> 10;
            ushort* dst = isK ? o1 : o0;
            const float sc = isK ? 1.0f : 0.125f;   // fold 1/sqrt(64) into Q
            const float* cr = ctab + (dh & 31);
            const float* sr = stab + (dh & 31);
#pragma unroll
            for (int mf = 0; mf < 4; ++mf) {
#pragma unroll
                for (int r = 0; r < 4; ++r) {
                    const int row = mbase + mf * 16 + g * 4 + r;
                    const int s = row & 2047, b = row >> 11;
                    const float v = acc[mf][nf][r] + bs;
                    const float p = __shfl_xor(v, 1);
                    const float cs = cr[s * 32], sn = sr[s * 32];
                    const float ov = (c & 1) ? v * cs + p * sn
                                             : v * cs - p * sn;
                    dst[(((size_t)(b * Hn + h)) * Sn + s) * DHn + dh] =
                        f2bf(ov * sc);
                }
            }
        } else {
            const int h = col >> 6, dh = col & 63;
#pragma unroll
            for (int mf = 0; mf < 4; ++mf) {
#pragma unroll
                for (int r = 0; r < 4; ++r) {
                    const int row = mbase + mf * 16 + g * 4 + r;
                    const int s = row & 2047, b = row >> 11;
                    const float v = acc[mf][nf][r] + bs;
                    o0[(((size_t)(b * Hn + h)) * DHn + dh) * Sn + s] = f2bf(v);
                }
            }
        }
    }
}

// ---------------------------------------------------------------------------
// MFMA flash attention, round 5:
//  - register double-buffered K/V fragment prefetch (hide L2/HBM latency
//    under MFMA+softmax of the current tile)
//  - XCD-locality swizzle: 1-D grid, block n -> bh=(n&7)*4+(n>>3)/32,
//    qblk=(n>>3)&31, so each XCD owns 4 heads (2MB K+V working set < 4MB L2)
// ---------------------------------------------------------------------------
__global__ __launch_bounds__(256) void attn_mfma(
    const ushort* __restrict__ Qg, const ushort* __restrict__ Kg,
    const ushort* __restrict__ Vt, float* __restrict__ Aw)
{
    __shared__ ushort Pw[4][16][40];   // padded: row stride 80B -> 2-way (free)

    const int tid = threadIdx.x;
    const int lane = tid & 63, w = tid >> 6;
    const int g = lane >> 4, c = lane & 15;
    const int n = blockIdx.x;
    const int bh = (n & 7) * 4 + ((n >> 3) >> 5);   // XCD-resident head groups
    const int qblk = (n >> 3) & 31;
    const int b = bh >> 4, h = bh & 15;
    const int q0 = qblk * 64 + w * 16;

    const size_t qrow = ((size_t)bh * Sn + q0 + c) * DHn;
    const bf16x8 qa0 = *(const bf16x8*)&Qg[qrow + g * 8];
    const bf16x8 qa1 = *(const bf16x8*)&Qg[qrow + 32 + g * 8];

    const ushort* Kb = Kg + (size_t)bh * Sn * DHn;
    const ushort* Vb = Vt + (size_t)bh * DHn * Sn;

    auto ldK = [&](int kb, int half, int sub) {
        return *(const bf16x8*)&Kb[(size_t)(kb + sub * 16 + c) * DHn + half * 32 + g * 8];
    };
    auto ldV = [&](int kb, int nf) {
        return *(const bf16x8*)&Vb[(size_t)(nf * 16 + c) * Sn + kb + g * 8];
    };

    f32x4 acc0 = {0.f, 0.f, 0.f, 0.f};
    f32x4 acc1 = acc0, acc2 = acc0, acc3 = acc0;
    float m[4] = {-1e30f, -1e30f, -1e30f, -1e30f};
    float l[4] = {0.f, 0.f, 0.f, 0.f};

    // prologue: tile 0 fragments
    bf16x8 kf00 = ldK(0, 0, 0), kf01 = ldK(0, 1, 0);
    bf16x8 kf10 = ldK(0, 0, 1), kf11 = ldK(0, 1, 1);
    bf16x8 vf0 = ldV(0, 0), vf1 = ldV(0, 1), vf2 = ldV(0, 2), vf3 = ldV(0, 3);

    for (int kb = 0; kb < Sn; kb += 32) {
        // ---- prefetch next tile (issued before any use of current tile) ----
        const int nkb = (kb + 32 < Sn) ? kb + 32 : kb;
        const bf16x8 a00 = ldK(nkb, 0, 0), a01 = ldK(nkb, 1, 0);
        const bf16x8 a10 = ldK(nkb, 0, 1), a11 = ldK(nkb, 1, 1);
        const bf16x8 nv0 = ldV(nkb, 0), nv1 = ldV(nkb, 1);
        const bf16x8 nv2 = ldV(nkb, 2), nv3 = ldV(nkb, 3);

        // ---- QK^T: two 16x16 score tiles ----
        const f32x4 z = {0.f, 0.f, 0.f, 0.f};
        f32x4 C0 = MFMA16(qa0, kf00, z);
        C0 = MFMA16(qa1, kf01, C0);
        f32x4 C1 = MFMA16(qa0, kf10, z);
        C1 = MFMA16(qa1, kf11, C1);

        // ---- online softmax ----
        float al[4];
#pragma unroll
        for (int r = 0; r < 4; ++r) {
            float v = fmaxf(C0[r], C1[r]);
            v = fmaxf(v, __shfl_xor(v, 1));
            v = fmaxf(v, __shfl_xor(v, 2));
            v = fmaxf(v, __shfl_xor(v, 4));
            v = fmaxf(v, __shfl_xor(v, 8));
            const float mn = fmaxf(m[r], v);
            const float a = __expf(m[r] - mn);
            const float e0 = __expf(C0[r] - mn);
            const float e1 = __expf(C1[r] - mn);
            float ps = e0 + e1;
            ps += __shfl_xor(ps, 1);
            ps += __shfl_xor(ps, 2);
            ps += __shfl_xor(ps, 4);
            ps += __shfl_xor(ps, 8);
            l[r] = l[r] * a + ps;
            m[r] = mn;
            al[r] = a;
            Pw[w][g * 4 + r][c] = f2bf(e0);
            Pw[w][g * 4 + r][16 + c] = f2bf(e1);
        }
#pragma unroll
        for (int r = 0; r < 4; ++r) {
            acc0[r] *= al[r];
            acc1[r] *= al[r];
            acc2[r] *= al[r];
            acc3[r] *= al[r];
        }

        // ---- PV ----
        const bf16x8 pa = *(const bf16x8*)&Pw[w][c][g * 8];
        acc0 = MFMA16(pa, vf0, acc0);
        acc1 = MFMA16(pa, vf1, acc1);
        acc2 = MFMA16(pa, vf2, acc2);
        acc3 = MFMA16(pa, vf3, acc3);

        // ---- rotate double buffer ----
        kf00 = a00; kf01 = a01; kf10 = a10; kf11 = a11;
        vf0 = nv0; vf1 = nv1; vf2 = nv2; vf3 = nv3;
    }

#pragma unroll
    for (int r = 0; r < 4; ++r) {
        const float inv = 1.0f / l[r];
        const int qs = q0 + g * 4 + r;
        float* dst = &Aw[((size_t)b * Sn + qs) * Dn + h * DHn + c];
        dst[0]  = acc0[r] * inv;
        dst[16] = acc1[r] * inv;
        dst[32] = acc2[r] * inv;
        dst[48] = acc3[r] * inv;
    }
}

// ---------------------------------------------------------------------------
// LayerNorm over D=1024 per (b,s) row; f32 output.
// ---------------------------------------------------------------------------
__global__ __launch_bounds__(256) void ln_kernel(
    const float* __restrict__ Aw, const float* __restrict__ gamma,
    const float* __restrict__ beta, float* __restrict__ out)
{
    const int row = blockIdx.x;
    const int tid = threadIdx.x;
    const int d0 = tid * 4;
    const float4 x = *(const float4*)&Aw[(size_t)row * Dn + d0];
    float sum = x.x + x.y + x.z + x.w;
    float sq = x.x * x.x + x.y * x.y + x.z * x.z + x.w * x.w;
    for (int off = 32; off; off >>= 1) {
        sum += __shfl_xor(sum, off);
        sq += __shfl_xor(sq, off);
    }
    __shared__ float red[8];
    const int lane = tid & 63, wave = tid >> 6;
    if (lane == 0) { red[wave] = sum; red[wave + 4] = sq; }
    __syncthreads();
    if (tid == 0) {
        red[0] = red[0] + red[1] + red[2] + red[3];
        red[4] = red[4] + red[5] + red[6] + red[7];
    }
    __syncthreads();
    sum = red[0]; sq = red[4];
    const float mu = sum * (1.0f / Dn);
    const float var = sq * (1.0f / Dn) - mu * mu;
    const float rs = rsqrtf(var + 1e-5f);

    const float4 gv = *(const float4*)&gamma[d0];
    const float4 bv = *(const float4*)&beta[d0];
    float4 ov;
    ov.x = (x.x - mu) * rs * gv.x + bv.x;
    ov.y = (x.y - mu) * rs * gv.y + bv.y;
    ov.z = (x.z - mu) * rs * gv.z + bv.z;
    ov.w = (x.w - mu) * rs * gv.w + bv.w;
    *(float4*)&out[(size_t)row * Dn + d0] = ov;
}

extern "C" void kernel_launch(void* const* d_in, const int* in_sizes, int n_in,
                              void* d_out, int out_size, void* d_ws, size_t ws_size,
                              hipStream_t stream)
{
    const float* x_qk = (const float*)d_in[0];
    const float* x_v  = (const float*)d_in[1];
    const float* W_qk = (const float*)d_in[2];
    const float* b_qk = (const float*)d_in[3];
    const float* W_v  = (const float*)d_in[4];
    const float* b_v  = (const float*)d_in[5];
    const float* g    = (const float*)d_in[6];
    const float* be   = (const float*)d_in[7];

    char* ws = (char*)d_ws;
    ushort* Qw    = (ushort*)(ws);                  //  8 MB bf16 (b,h,s,dh)
    ushort* Kw    = (ushort*)(ws + (8u  << 20));    //  8 MB bf16 (b,h,s,dh)
    ushort* Vtw   = (ushort*)(ws + (16u << 20));    //  8 MB bf16 (b,h,dh,s)
    float*  Aw    = (float*) (ws + (24u << 20));    // 16 MB f32  (b,s,D)
    ushort* xqkB  = (ushort*)(ws + (40u << 20));    //  8 MB bf16 [M][K]
    ushort* xvB   = (ushort*)(ws + (48u << 20));    //  8 MB bf16 [M][K]
    ushort* WqkT  = (ushort*)(ws + (56u << 20));    //  4 MB bf16 [2048][1024]
    ushort* WvT   = (ushort*)(ws + (60u << 20));    //  2 MB bf16 [1024][1024]
    float*  ctab  = (float*) (ws + (62u << 20));    // 256 KB
    float*  stab  = (float*) (ws + (62u << 20) + (256u << 10));

    rope_tab<<<256, 256, 0, stream>>>(ctab, stab);
    cvt_bf16<<<2048, 256, 0, stream>>>(x_qk, xqkB);
    cvt_bf16<<<2048, 256, 0, stream>>>(x_v, xvB);
    transpose_bf16<<<dim3(64, 32), dim3(32, 8), 0, stream>>>(W_qk, WqkT, Kd, 2048);
    transpose_bf16<<<dim3(32, 32), dim3(32, 8), 0, stream>>>(W_v, WvT, Kd, 1024);

    gemm_mfma<0><<<dim3(16, 32), 256, 0, stream>>>(
        xqkB, WqkT, b_qk, ctab, stab, Qw, Kw);
    gemm_mfma<1><<<dim3(8, 32), 256, 0, stream>>>(
        xvB, WvT, b_v, ctab, stab, Vtw, nullptr);

    attn_mfma<<<1024, 256, 0, stream>>>(Qw, Kw, Vtw, Aw);
    ln_kernel<<<Bn * Sn, 256, 0, stream>>>(Aw, g, be, (float*)d_out);
}

// Round 6
// 266.010 us; speedup vs baseline: 1.5758x; 1.5758x over previous
//
#include <hip/hip_runtime.h>
#include <hip/hip_bf16.h>

// B=2, S=2048, D=1024, H=16, DH=64. f32 in/out; bf16 intermediates for MFMA.
#define Bn 2
#define Sn 2048
#define Dn 1024
#define Hn 16
#define DHn 64
#define Kd 1024
#define Mn (Bn * Sn)
#define LN10K 9.210340371976184f

typedef __attribute__((ext_vector_type(8))) short bf16x8;  // MFMA A/B frag
typedef __attribute__((ext_vector_type(4))) float f32x4;   // MFMA C/D frag

static __device__ __forceinline__ ushort f2bf(float f) {
    uint u = __float_as_uint(f);
    u += 0x7fff + ((u >> 16) & 1);   // round-nearest-even
    return (ushort)(u >> 16);
}

#define MFMA16(a, b, c) __builtin_amdgcn_mfma_f32_16x16x32_bf16((a), (b), (c), 0, 0, 0)

// XOR swizzle for [64 rows][128B] LDS tiles: spreads the 128B row stride
// across banks so 16-lane column reads are ~2-way instead of 16-way.
static __device__ __forceinline__ int swz(int row, int col16) {
    return row * 128 + (((col16) * 16) ^ ((row & 7) << 4));
}

// ---------------------------------------------------------------------------
// RoPE table: ctab/stab[s][fe], s in [0,2048), fe in [0,32).
// ---------------------------------------------------------------------------
__global__ __launch_bounds__(256) void rope_tab(float* __restrict__ ct,
                                                float* __restrict__ st)
{
    const int idx = blockIdx.x * 256 + threadIdx.x;
    const int s = idx >> 5, fe = idx & 31;
    const float f = expf(-LN10K * (float)fe / 32.0f);
    const float a = (float)s * f;
    ct[idx] = cosf(a);
    st[idx] = sinf(a);
}

// ---------------------------------------------------------------------------
// f32 -> bf16 elementwise (8 per thread).
// ---------------------------------------------------------------------------
__global__ __launch_bounds__(256) void cvt_bf16(const float* __restrict__ in,
                                                ushort* __restrict__ out)
{
    const size_t i = ((size_t)blockIdx.x * 256 + threadIdx.x) * 8;
    const float4 a = *(const float4*)(in + i);
    const float4 b = *(const float4*)(in + i + 4);
    ushort4 lo = make_ushort4(f2bf(a.x), f2bf(a.y), f2bf(a.z), f2bf(a.w));
    ushort4 hi = make_ushort4(f2bf(b.x), f2bf(b.y), f2bf(b.z), f2bf(b.w));
    *(ushort4*)(out + i) = lo;
    *(ushort4*)(out + i + 4) = hi;
}

// ---------------------------------------------------------------------------
// Transpose + convert: in f32 [R][C] -> out bf16 [C][R]. 32x32 tiles.
// ---------------------------------------------------------------------------
__global__ __launch_bounds__(256) void transpose_bf16(
    const float* __restrict__ in, ushort* __restrict__ out, int R, int C)
{
    __shared__ ushort t[32][33];
    const int n0 = blockIdx.x * 32, k0 = blockIdx.y * 32;
    const int x = threadIdx.x, y = threadIdx.y;
#pragma unroll
    for (int i = 0; i < 4; ++i)
        t[y + 8 * i][x] = f2bf(in[(size_t)(k0 + y + 8 * i) * C + n0 + x]);
    __syncthreads();
#pragma unroll
    for (int i = 0; i < 4; ++i)
        out[(size_t)(n0 + y + 8 * i) * R + k0 + x] = t[x][y + 8 * i];
}

// ---------------------------------------------------------------------------
// MFMA GEMM, LDS-free (as round 4).
// ---------------------------------------------------------------------------
template <int MODE>
__global__ __launch_bounds__(256) void gemm_mfma(
    const ushort* __restrict__ A, const ushort* __restrict__ Bt,
    const float* __restrict__ bias, const float* __restrict__ ctab,
    const float* __restrict__ stab, ushort* __restrict__ o0,
    ushort* __restrict__ o1)
{
    const int tid = threadIdx.x;
    const int lane = tid & 63, w = tid >> 6;
    const int g = lane >> 4, c = lane & 15;
    const int mbase = blockIdx.y * 128 + (w >> 1) * 64;
    const int nbase = blockIdx.x * 128 + (w & 1) * 64;

    f32x4 acc[4][4];
#pragma unroll
    for (int mf = 0; mf < 4; ++mf)
#pragma unroll
        for (int nf = 0; nf < 4; ++nf)
            acc[mf][nf] = (f32x4){0.f, 0.f, 0.f, 0.f};

    const ushort* Ap = A + (size_t)(mbase + c) * Kd + g * 8;
    const ushort* Bp = Bt + (size_t)(nbase + c) * Kd + g * 8;

    for (int k0 = 0; k0 < Kd; k0 += 32) {
        bf16x8 af[4], bfr[4];
#pragma unroll
        for (int mf = 0; mf < 4; ++mf)
            af[mf] = *(const bf16x8*)(Ap + (size_t)mf * 16 * Kd + k0);
#pragma unroll
        for (int nf = 0; nf < 4; ++nf)
            bfr[nf] = *(const bf16x8*)(Bp + (size_t)nf * 16 * Kd + k0);
#pragma unroll
        for (int mf = 0; mf < 4; ++mf)
#pragma unroll
            for (int nf = 0; nf < 4; ++nf)
                acc[mf][nf] = MFMA16(af[mf], bfr[nf], acc[mf][nf]);
    }

#pragma unroll
    for (int nf = 0; nf < 4; ++nf) {
        const int col = nbase + nf * 16 + c;
        const float bs = bias[col];
        if (MODE == 0) {
            const int dh = col & 63, h = (col >> 6) & 15, isK = col >> 10;
            ushort* dst = isK ? o1 : o0;
            const float sc = isK ? 1.0f : 0.125f;   // fold 1/sqrt(64) into Q
            const float* cr = ctab + (dh & 31);
            const float* sr = stab + (dh & 31);
#pragma unroll
            for (int mf = 0; mf < 4; ++mf) {
#pragma unroll
                for (int r = 0; r < 4; ++r) {
                    const int row = mbase + mf * 16 + g * 4 + r;
                    const int s = row & 2047, b = row >> 11;
                    const float v = acc[mf][nf][r] + bs;
                    const float p = __shfl_xor(v, 1);
                    const float cs = cr[s * 32], sn = sr[s * 32];
                    const float ov = (c & 1) ? v * cs + p * sn
                                             : v * cs - p * sn;
                    dst[(((size_t)(b * Hn + h)) * Sn + s) * DHn + dh] =
                        f2bf(ov * sc);
                }
            }
        } else {
            const int h = col >> 6, dh = col & 63;
#pragma unroll
            for (int mf = 0; mf < 4; ++mf) {
#pragma unroll
                for (int r = 0; r < 4; ++r) {
                    const int row = mbase + mf * 16 + g * 4 + r;
                    const int s = row & 2047, b = row >> 11;
                    const float v = acc[mf][nf][r] + bs;
                    o0[(((size_t)(b * Hn + h)) * DHn + dh) * Sn + s] = f2bf(v);
                }
            }
        }
    }
}

// ---------------------------------------------------------------------------
// MFMA flash attention, round 6: KVBLK=64, K/V cooperatively staged into
// swizzled LDS (double-buffered, reg-staged T14 split), 4 waves x 16 q-rows.
// Per iter per wave: 8 QK MFMA + softmax + 8 PV MFMA; 32 iters.
// ---------------------------------------------------------------------------
__global__ __launch_bounds__(256) void attn_mfma(
    const ushort* __restrict__ Qg, const ushort* __restrict__ Kg,
    const ushort* __restrict__ Vt, float* __restrict__ Aw)
{
    __shared__ char Kt[2][8192];        // [64 k-rows][64 d] bf16, swizzled
    __shared__ char Vtile[2][8192];     // [64 dh]   [64 kv] bf16, swizzled
    __shared__ ushort Pw[4][16][72];    // per-wave P, 144B rows

    const int tid = threadIdx.x;
    const int lane = tid & 63, w = tid >> 6;
    const int g = lane >> 4, c = lane & 15;
    const int bh = blockIdx.y;
    const int b = bh >> 4, h = bh & 15;
    const int q0 = blockIdx.x * 64 + w * 16;

    const size_t qrow = ((size_t)bh * Sn + q0 + c) * DHn;
    const bf16x8 qa0 = *(const bf16x8*)&Qg[qrow + g * 8];
    const bf16x8 qa1 = *(const bf16x8*)&Qg[qrow + 32 + g * 8];

    const ushort* Kb = Kg + (size_t)bh * Sn * DHn;
    const ushort* Vb = Vt + (size_t)bh * DHn * Sn;

    // staging map: thread -> (row, 16B-col); 2 rounds cover 64 rows.
    const int srow = tid >> 3;          // 0..31
    const int scol = tid & 7;           // 0..7

    // prologue: stage tile 0 into buffer 0
    {
        const bf16x8 k0 = *(const bf16x8*)&Kb[(size_t)srow * DHn + scol * 8];
        const bf16x8 k1 = *(const bf16x8*)&Kb[(size_t)(srow + 32) * DHn + scol * 8];
        const bf16x8 v0 = *(const bf16x8*)&Vb[(size_t)srow * Sn + scol * 8];
        const bf16x8 v1 = *(const bf16x8*)&Vb[(size_t)(srow + 32) * Sn + scol * 8];
        *(bf16x8*)&Kt[0][swz(srow, scol)] = k0;
        *(bf16x8*)&Kt[0][swz(srow + 32, scol)] = k1;
        *(bf16x8*)&Vtile[0][swz(srow, scol)] = v0;
        *(bf16x8*)&Vtile[0][swz(srow + 32, scol)] = v1;
    }
    __syncthreads();

    f32x4 acc[4];
#pragma unroll
    for (int nf = 0; nf < 4; ++nf) acc[nf] = (f32x4){0.f, 0.f, 0.f, 0.f};
    float m[4] = {-1e30f, -1e30f, -1e30f, -1e30f};
    float l[4] = {0.f, 0.f, 0.f, 0.f};

    for (int t = 0; t < Sn / 64; ++t) {
        const int cur = t & 1;
        const bool pf = (t + 1 < Sn / 64);

        // ---- issue next tile's global loads early (complete by barrier#1) --
        bf16x8 kr0, kr1, vr0, vr1;
        if (pf) {
            const int kb2 = (t + 1) * 64;
            kr0 = *(const bf16x8*)&Kb[(size_t)(kb2 + srow) * DHn + scol * 8];
            kr1 = *(const bf16x8*)&Kb[(size_t)(kb2 + srow + 32) * DHn + scol * 8];
            vr0 = *(const bf16x8*)&Vb[(size_t)srow * Sn + kb2 + scol * 8];
            vr1 = *(const bf16x8*)&Vb[(size_t)(srow + 32) * Sn + kb2 + scol * 8];
            asm volatile("" ::: "memory");   // pin load issue before compute
        }

        // ---- QK^T: 4 score tiles (16q x 16k each) ----
        bf16x8 kf[4][2];
#pragma unroll
        for (int sub = 0; sub < 4; ++sub) {
            kf[sub][0] = *(const bf16x8*)&Kt[cur][swz(sub * 16 + c, g)];
            kf[sub][1] = *(const bf16x8*)&Kt[cur][swz(sub * 16 + c, 4 + g)];
        }
        const f32x4 z = {0.f, 0.f, 0.f, 0.f};
        f32x4 C[4];
#pragma unroll
        for (int sub = 0; sub < 4; ++sub) {
            C[sub] = MFMA16(qa0, kf[sub][0], z);
            C[sub] = MFMA16(qa1, kf[sub][1], C[sub]);
        }

        // ---- online softmax over 64 k-cols (16 lanes x 4 tiles) ----
        float al[4];
#pragma unroll
        for (int r = 0; r < 4; ++r) {
            float v = fmaxf(fmaxf(C[0][r], C[1][r]), fmaxf(C[2][r], C[3][r]));
            v = fmaxf(v, __shfl_xor(v, 1));
            v = fmaxf(v, __shfl_xor(v, 2));
            v = fmaxf(v, __shfl_xor(v, 4));
            v = fmaxf(v, __shfl_xor(v, 8));
            const float mn = fmaxf(m[r], v);
            const float a = __expf(m[r] - mn);
            float e0 = __expf(C[0][r] - mn);
            float e1 = __expf(C[1][r] - mn);
            float e2 = __expf(C[2][r] - mn);
            float e3 = __expf(C[3][r] - mn);
            float ps = (e0 + e1) + (e2 + e3);
            ps += __shfl_xor(ps, 1);
            ps += __shfl_xor(ps, 2);
            ps += __shfl_xor(ps, 4);
            ps += __shfl_xor(ps, 8);
            l[r] = l[r] * a + ps;
            m[r] = mn;
            al[r] = a;
            const int pr = g * 4 + r;
            Pw[w][pr][c] = f2bf(e0);
            Pw[w][pr][16 + c] = f2bf(e1);
            Pw[w][pr][32 + c] = f2bf(e2);
            Pw[w][pr][48 + c] = f2bf(e3);
        }
#pragma unroll
        for (int nf = 0; nf < 4; ++nf)
#pragma unroll
            for (int r = 0; r < 4; ++r) acc[nf][r] *= al[r];

        // ---- PV: P[16x64] @ V[64 kv x 64 dh] via V^T tile ----
        const bf16x8 pa0 = *(const bf16x8*)&Pw[w][c][g * 8];
        const bf16x8 pa1 = *(const bf16x8*)&Pw[w][c][32 + g * 8];
#pragma unroll
        for (int nf = 0; nf < 4; ++nf) {
            const bf16x8 vfa = *(const bf16x8*)&Vtile[cur][swz(nf * 16 + c, g)];
            const bf16x8 vfb = *(const bf16x8*)&Vtile[cur][swz(nf * 16 + c, 4 + g)];
            acc[nf] = MFMA16(pa0, vfa, acc[nf]);
            acc[nf] = MFMA16(pa1, vfb, acc[nf]);
        }

        __syncthreads();   // #1: all reads of buf[cur] done (drains prefetch)
        if (pf) {
            const int nxt = cur ^ 1;
            *(bf16x8*)&Kt[nxt][swz(srow, scol)] = kr0;
            *(bf16x8*)&Kt[nxt][swz(srow + 32, scol)] = kr1;
            *(bf16x8*)&Vtile[nxt][swz(srow, scol)] = vr0;
            *(bf16x8*)&Vtile[nxt][swz(srow + 32, scol)] = vr1;
        }
        __syncthreads();   // #2: staged writes visible
    }

    // ---- epilogue ----
#pragma unroll
    for (int r = 0; r < 4; ++r) {
        const float inv = 1.0f / l[r];
        const int qs = q0 + g * 4 + r;
        float* dst = &Aw[((size_t)b * Sn + qs) * Dn + h * DHn + c];
        dst[0]  = acc[0][r] * inv;
        dst[16] = acc[1][r] * inv;
        dst[32] = acc[2][r] * inv;
        dst[48] = acc[3][r] * inv;
    }
}

// ---------------------------------------------------------------------------
// LayerNorm over D=1024 per (b,s) row; f32 output.
// ---------------------------------------------------------------------------
__global__ __launch_bounds__(256) void ln_kernel(
    const float* __restrict__ Aw, const float* __restrict__ gamma,
    const float* __restrict__ beta, float* __restrict__ out)
{
    const int row = blockIdx.x;
    const int tid = threadIdx.x;
    const int d0 = tid * 4;
    const float4 x = *(const float4*)&Aw[(size_t)row * Dn + d0];
    float sum = x.x + x.y + x.z + x.w;
    float sq = x.x * x.x + x.y * x.y + x.z * x.z + x.w * x.w;
    for (int off = 32; off; off >>= 1) {
        sum += __shfl_xor(sum, off);
        sq += __shfl_xor(sq, off);
    }
    __shared__ float red[8];
    const int lane = tid & 63, wave = tid >> 6;
    if (lane == 0) { red[wave] = sum; red[wave + 4] = sq; }
    __syncthreads();
    if (tid == 0) {
        red[0] = red[0] + red[1] + red[2] + red[3];
        red[4] = red[4] + red[5] + red[6] + red[7];
    }
    __syncthreads();
    sum = red[0]; sq = red[4];
    const float mu = sum * (1.0f / Dn);
    const float var = sq * (1.0f / Dn) - mu * mu;
    const float rs = rsqrtf(var + 1e-5f);

    const float4 gv = *(const float4*)&gamma[d0];
    const float4 bv = *(const float4*)&beta[d0];
    float4 ov;
    ov.x = (x.x - mu) * rs * gv.x + bv.x;
    ov.y = (x.y - mu) * rs * gv.y + bv.y;
    ov.z = (x.z - mu) * rs * gv.z + bv.z;
    ov.w = (x.w - mu) * rs * gv.w + bv.w;
    *(float4*)&out[(size_t)row * Dn + d0] = ov;
}

extern "C" void kernel_launch(void* const* d_in, const int* in_sizes, int n_in,
                              void* d_out, int out_size, void* d_ws, size_t ws_size,
                              hipStream_t stream)
{
    const float* x_qk = (const float*)d_in[0];
    const float* x_v  = (const float*)d_in[1];
    const float* W_qk = (const float*)d_in[2];
    const float* b_qk = (const float*)d_in[3];
    const float* W_v  = (const float*)d_in[4];
    const float* b_v  = (const float*)d_in[5];
    const float* g    = (const float*)d_in[6];
    const float* be   = (const float*)d_in[7];

    char* ws = (char*)d_ws;
    ushort* Qw    = (ushort*)(ws);                  //  8 MB bf16 (b,h,s,dh)
    ushort* Kw    = (ushort*)(ws + (8u  << 20));    //  8 MB bf16 (b,h,s,dh)
    ushort* Vtw   = (ushort*)(ws + (16u << 20));    //  8 MB bf16 (b,h,dh,s)
    float*  Aw    = (float*) (ws + (24u << 20));    // 16 MB f32  (b,s,D)
    ushort* xqkB  = (ushort*)(ws + (40u << 20));    //  8 MB bf16 [M][K]
    ushort* xvB   = (ushort*)(ws + (48u << 20));    //  8 MB bf16 [M][K]
    ushort* WqkT  = (ushort*)(ws + (56u << 20));    //  4 MB bf16 [2048][1024]
    ushort* WvT   = (ushort*)(ws + (60u << 20));    //  2 MB bf16 [1024][1024]
    float*  ctab  = (float*) (ws + (62u << 20));    // 256 KB
    float*  stab  = (float*) (ws + (62u << 20) + (256u << 10));

    rope_tab<<<256, 256, 0, stream>>>(ctab, stab);
    cvt_bf16<<<2048, 256, 0, stream>>>(x_qk, xqkB);
    cvt_bf16<<<2048, 256, 0, stream>>>(x_v, xvB);
    transpose_bf16<<<dim3(64, 32), dim3(32, 8), 0, stream>>>(W_qk, WqkT, Kd, 2048);
    transpose_bf16<<<dim3(32, 32), dim3(32, 8), 0, stream>>>(W_v, WvT, Kd, 1024);

    gemm_mfma<0><<<dim3(16, 32), 256, 0, stream>>>(
        xqkB, WqkT, b_qk, ctab, stab, Qw, Kw);
    gemm_mfma<1><<<dim3(8, 32), 256, 0, stream>>>(
        xvB, WvT, b_v, ctab, stab, Vtw, nullptr);

    attn_mfma<<<dim3(32, 32), 256, 0, stream>>>(Qw, Kw, Vtw, Aw);
    ln_kernel<<<Bn * Sn, 256, 0, stream>>>(Aw, g, be, (float*)d_out);
}

// Round 7
// 227.320 us; speedup vs baseline: 1.8440x; 1.1702x over previous
//
#include <hip/hip_runtime.h>
#include <hip/hip_bf16.h>

// B=2, S=2048, D=1024, H=16, DH=64. f32 in/out; bf16 intermediates for MFMA.
#define Bn 2
#define Sn 2048
#define Dn 1024
#define Hn 16
#define DHn 64
#define Kd 1024
#define Mn (Bn * Sn)
#define LN10K 9.210340371976184f

typedef __attribute__((ext_vector_type(8))) short bf16x8;  // MFMA A/B frag
typedef __attribute__((ext_vector_type(4))) float f32x4;   // MFMA C/D frag

static __device__ __forceinline__ ushort f2bf(float f) {
    uint u = __float_as_uint(f);
    u += 0x7fff + ((u >> 16) & 1);   // round-nearest-even
    return (ushort)(u >> 16);
}
// packed f32x2 -> bf16x2 (RNE), lo = a, hi = b
static __device__ __forceinline__ uint cvtpk(float a, float b) {
    uint r;
    asm("v_cvt_pk_bf16_f32 %0, %1, %2" : "=v"(r) : "v"(a), "v"(b));
    return r;
}

#define MFMA16(a, b, c) __builtin_amdgcn_mfma_f32_16x16x32_bf16((a), (b), (c), 0, 0, 0)

// XOR swizzle for [64 rows][128B] LDS tiles (16B granules).
static __device__ __forceinline__ int swz(int row, int col16) {
    return row * 128 + (((col16) * 16) ^ ((row & 7) << 4));
}

// ---------------------------------------------------------------------------
__global__ __launch_bounds__(256) void rope_tab(float* __restrict__ ct,
                                                float* __restrict__ st)
{
    const int idx = blockIdx.x * 256 + threadIdx.x;
    const int s = idx >> 5, fe = idx & 31;
    const float f = expf(-LN10K * (float)fe / 32.0f);
    const float a = (float)s * f;
    ct[idx] = cosf(a);
    st[idx] = sinf(a);
}

__global__ __launch_bounds__(256) void cvt_bf16(const float* __restrict__ in,
                                                ushort* __restrict__ out)
{
    const size_t i = ((size_t)blockIdx.x * 256 + threadIdx.x) * 8;
    const float4 a = *(const float4*)(in + i);
    const float4 b = *(const float4*)(in + i + 4);
    ushort4 lo = make_ushort4(f2bf(a.x), f2bf(a.y), f2bf(a.z), f2bf(a.w));
    ushort4 hi = make_ushort4(f2bf(b.x), f2bf(b.y), f2bf(b.z), f2bf(b.w));
    *(ushort4*)(out + i) = lo;
    *(ushort4*)(out + i + 4) = hi;
}

__global__ __launch_bounds__(256) void transpose_bf16(
    const float* __restrict__ in, ushort* __restrict__ out, int R, int C)
{
    __shared__ ushort t[32][33];
    const int n0 = blockIdx.x * 32, k0 = blockIdx.y * 32;
    const int x = threadIdx.x, y = threadIdx.y;
#pragma unroll
    for (int i = 0; i < 4; ++i)
        t[y + 8 * i][x] = f2bf(in[(size_t)(k0 + y + 8 * i) * C + n0 + x]);
    __syncthreads();
#pragma unroll
    for (int i = 0; i < 4; ++i)
        out[(size_t)(n0 + y + 8 * i) * R + k0 + x] = t[x][y + 8 * i];
}

// ---------------------------------------------------------------------------
// MFMA GEMM, LDS-free (as round 4).
// ---------------------------------------------------------------------------
template <int MODE>
__global__ __launch_bounds__(256) void gemm_mfma(
    const ushort* __restrict__ A, const ushort* __restrict__ Bt,
    const float* __restrict__ bias, const float* __restrict__ ctab,
    const float* __restrict__ stab, ushort* __restrict__ o0,
    ushort* __restrict__ o1)
{
    const int tid = threadIdx.x;
    const int lane = tid & 63, w = tid >> 6;
    const int g = lane >> 4, c = lane & 15;
    const int mbase = blockIdx.y * 128 + (w >> 1) * 64;
    const int nbase = blockIdx.x * 128 + (w & 1) * 64;

    f32x4 acc[4][4];
#pragma unroll
    for (int mf = 0; mf < 4; ++mf)
#pragma unroll
        for (int nf = 0; nf < 4; ++nf)
            acc[mf][nf] = (f32x4){0.f, 0.f, 0.f, 0.f};

    const ushort* Ap = A + (size_t)(mbase + c) * Kd + g * 8;
    const ushort* Bp = Bt + (size_t)(nbase + c) * Kd + g * 8;

    for (int k0 = 0; k0 < Kd; k0 += 32) {
        bf16x8 af[4], bfr[4];
#pragma unroll
        for (int mf = 0; mf < 4; ++mf)
            af[mf] = *(const bf16x8*)(Ap + (size_t)mf * 16 * Kd + k0);
#pragma unroll
        for (int nf = 0; nf < 4; ++nf)
            bfr[nf] = *(const bf16x8*)(Bp + (size_t)nf * 16 * Kd + k0);
#pragma unroll
        for (int mf = 0; mf < 4; ++mf)
#pragma unroll
            for (int nf = 0; nf < 4; ++nf)
                acc[mf][nf] = MFMA16(af[mf], bfr[nf], acc[mf][nf]);
    }

#pragma unroll
    for (int nf = 0; nf < 4; ++nf) {
        const int col = nbase + nf * 16 + c;
        const float bs = bias[col];
        if (MODE == 0) {
            const int dh = col & 63, h = (col >> 6) & 15, isK = col >> 10;
            ushort* dst = isK ? o1 : o0;
            const float sc = isK ? 1.0f : 0.125f;   // fold 1/sqrt(64) into Q
            const float* cr = ctab + (dh & 31);
            const float* sr = stab + (dh & 31);
#pragma unroll
            for (int mf = 0; mf < 4; ++mf) {
#pragma unroll
                for (int r = 0; r < 4; ++r) {
                    const int row = mbase + mf * 16 + g * 4 + r;
                    const int s = row & 2047, b = row >> 11;
                    const float v = acc[mf][nf][r] + bs;
                    const float p = __shfl_xor(v, 1);
                    const float cs = cr[s * 32], sn = sr[s * 32];
                    const float ov = (c & 1) ? v * cs + p * sn
                                             : v * cs - p * sn;
                    dst[(((size_t)(b * Hn + h)) * Sn + s) * DHn + dh] =
                        f2bf(ov * sc);
                }
            }
        } else {
            const int h = col >> 6, dh = col & 63;
#pragma unroll
            for (int mf = 0; mf < 4; ++mf) {
#pragma unroll
                for (int r = 0; r < 4; ++r) {
                    const int row = mbase + mf * 16 + g * 4 + r;
                    const int s = row & 2047, b = row >> 11;
                    const float v = acc[mf][nf][r] + bs;
                    o0[(((size_t)(b * Hn + h)) * DHn + dh) * Sn + s] = f2bf(v);
                }
            }
        }
    }
}

// ---------------------------------------------------------------------------
// MFMA flash attention, round 7. KVBLK=64, LDS-staged K/V (double-buffered).
// kv-axis of P and V stored permuted by pi(u) = 16*(u&3) + (u>>2) — the
// contraction is invariant; this makes each lane's 4 P values contiguous so
// the P write is 2 cvt_pk + 1 ds_write_b64 per row.
// Softmax: deferred l-reduction (per-lane partials, epilogue reduce) and
// defer-max rescale skip (T13, THR=8).
// ---------------------------------------------------------------------------
__global__ __launch_bounds__(256) void attn_mfma(
    const ushort* __restrict__ Qg, const ushort* __restrict__ Kg,
    const ushort* __restrict__ Vt, float* __restrict__ Aw)
{
    __shared__ char Kt[2][8192];        // [64 kv][64 d] bf16, swizzled
    __shared__ char Vtile[2][8192];     // [64 dh][64 u]  bf16, swizzled, pi-permuted
    __shared__ ushort Pw[4][16][72];    // per-wave P [q][u], 144B rows

    const int tid = threadIdx.x;
    const int lane = tid & 63, w = tid >> 6;
    const int g = lane >> 4, c = lane & 15;
    const int bh = blockIdx.y;
    const int b = bh >> 4, h = bh & 15;
    const int q0 = blockIdx.x * 64 + w * 16;

    const size_t qrow = ((size_t)bh * Sn + q0 + c) * DHn;
    const bf16x8 qa0 = *(const bf16x8*)&Qg[qrow + g * 8];
    const bf16x8 qa1 = *(const bf16x8*)&Qg[qrow + 32 + g * 8];

    const ushort* Kb = Kg + (size_t)bh * Sn * DHn;
    const ushort* Vb = Vt + (size_t)bh * DHn * Sn;

    // staging map: thread -> (row, 16B-col)
    const int srow = tid >> 3;          // 0..31
    const int scol = tid & 7;           // 0..7

    // V scatter-store with pi permutation: element (tile kv, row dh) -> col u
    auto stV = [&](char* dst, const bf16x8 v, int row) {
#pragma unroll
        for (int i = 0; i < 8; ++i) {
            const int kvl = scol * 8 + i;                 // tile-local kv
            const int u = 4 * (kvl & 15) + (kvl >> 4);
            const int byte = row * 128 + ((2 * u) ^ ((row & 7) << 4));
            *(ushort*)&dst[byte] = (ushort)v[i];
        }
    };

    // prologue: stage tile 0 into buffer 0
    {
        const bf16x8 k0 = *(const bf16x8*)&Kb[(size_t)srow * DHn + scol * 8];
        const bf16x8 k1 = *(const bf16x8*)&Kb[(size_t)(srow + 32) * DHn + scol * 8];
        const bf16x8 v0 = *(const bf16x8*)&Vb[(size_t)srow * Sn + scol * 8];
        const bf16x8 v1 = *(const bf16x8*)&Vb[(size_t)(srow + 32) * Sn + scol * 8];
        *(bf16x8*)&Kt[0][swz(srow, scol)] = k0;
        *(bf16x8*)&Kt[0][swz(srow + 32, scol)] = k1;
        stV(Vtile[0], v0, srow);
        stV(Vtile[0], v1, srow + 32);
    }
    __syncthreads();

    f32x4 acc[4];
#pragma unroll
    for (int nf = 0; nf < 4; ++nf) acc[nf] = (f32x4){0.f, 0.f, 0.f, 0.f};
    float m[4] = {-1e30f, -1e30f, -1e30f, -1e30f};
    float lp[4] = {0.f, 0.f, 0.f, 0.f};   // per-lane partial denominators

    for (int t = 0; t < Sn / 64; ++t) {
        const int cur = t & 1;
        const bool pf = (t + 1 < Sn / 64);

        // ---- issue next tile's global loads early ----
        bf16x8 kr0, kr1, vr0, vr1;
        if (pf) {
            const int kb2 = (t + 1) * 64;
            kr0 = *(const bf16x8*)&Kb[(size_t)(kb2 + srow) * DHn + scol * 8];
            kr1 = *(const bf16x8*)&Kb[(size_t)(kb2 + srow + 32) * DHn + scol * 8];
            vr0 = *(const bf16x8*)&Vb[(size_t)srow * Sn + kb2 + scol * 8];
            vr1 = *(const bf16x8*)&Vb[(size_t)(srow + 32) * Sn + kb2 + scol * 8];
            asm volatile("" ::: "memory");   // pin load issue before compute
        }

        // ---- QK^T: 4 score tiles (16q x 16k each) ----
        bf16x8 kf[4][2];
#pragma unroll
        for (int sub = 0; sub < 4; ++sub) {
            kf[sub][0] = *(const bf16x8*)&Kt[cur][swz(sub * 16 + c, g)];
            kf[sub][1] = *(const bf16x8*)&Kt[cur][swz(sub * 16 + c, 4 + g)];
        }
        const f32x4 z = {0.f, 0.f, 0.f, 0.f};
        f32x4 C[4];
#pragma unroll
        for (int sub = 0; sub < 4; ++sub) {
            C[sub] = MFMA16(qa0, kf[sub][0], z);
            C[sub] = MFMA16(qa1, kf[sub][1], C[sub]);
        }

        // ---- row maxima (16 lanes span kv) ----
        float pmax[4];
        int need = 0;
#pragma unroll
        for (int r = 0; r < 4; ++r) {
            float v = fmaxf(fmaxf(C[0][r], C[1][r]), fmaxf(C[2][r], C[3][r]));
            v = fmaxf(v, __shfl_xor(v, 1));
            v = fmaxf(v, __shfl_xor(v, 2));
            v = fmaxf(v, __shfl_xor(v, 4));
            v = fmaxf(v, __shfl_xor(v, 8));
            pmax[r] = v;
            need |= (v > m[r] + 8.0f);
        }
        // ---- defer-max: rescale only when some row exceeds m+8 ----
        if (__any(need)) {
#pragma unroll
            for (int r = 0; r < 4; ++r) {
                const float mn = fmaxf(m[r], pmax[r]);
                const float a = __expf(m[r] - mn);
                m[r] = mn;
                lp[r] *= a;
#pragma unroll
                for (int nf = 0; nf < 4; ++nf) acc[nf][r] *= a;
            }
        }

        // ---- exp + P write (pi layout: lane's 4 values contiguous) ----
#pragma unroll
        for (int r = 0; r < 4; ++r) {
            const float e0 = __expf(C[0][r] - m[r]);
            const float e1 = __expf(C[1][r] - m[r]);
            const float e2 = __expf(C[2][r] - m[r]);
            const float e3 = __expf(C[3][r] - m[r]);
            lp[r] += (e0 + e1) + (e2 + e3);
            uint2 pk;
            pk.x = cvtpk(e0, e1);
            pk.y = cvtpk(e2, e3);
            *(uint2*)&Pw[w][g * 4 + r][4 * c] = pk;
        }

        // ---- PV: A = P[q][u] frag, B = V[dh][u] frag (same pi on u) ----
        const bf16x8 pa0 = *(const bf16x8*)&Pw[w][c][g * 8];
        const bf16x8 pa1 = *(const bf16x8*)&Pw[w][c][32 + g * 8];
#pragma unroll
        for (int nf = 0; nf < 4; ++nf) {
            const bf16x8 vfa = *(const bf16x8*)&Vtile[cur][swz(nf * 16 + c, g)];
            const bf16x8 vfb = *(const bf16x8*)&Vtile[cur][swz(nf * 16 + c, 4 + g)];
            acc[nf] = MFMA16(pa0, vfa, acc[nf]);
            acc[nf] = MFMA16(pa1, vfb, acc[nf]);
        }

        __syncthreads();   // #1: all reads of buf[cur] done
        if (pf) {
            const int nxt = cur ^ 1;
            *(bf16x8*)&Kt[nxt][swz(srow, scol)] = kr0;
            *(bf16x8*)&Kt[nxt][swz(srow + 32, scol)] = kr1;
            stV(Vtile[nxt], vr0, srow);
            stV(Vtile[nxt], vr1, srow + 32);
        }
        __syncthreads();   // #2: staged writes visible
    }

    // ---- epilogue: reduce per-lane partials, divide, store ----
#pragma unroll
    for (int r = 0; r < 4; ++r) {
        float lv = lp[r];
        lv += __shfl_xor(lv, 1);
        lv += __shfl_xor(lv, 2);
        lv += __shfl_xor(lv, 4);
        lv += __shfl_xor(lv, 8);
        const float inv = 1.0f / lv;
        const int qs = q0 + g * 4 + r;
        float* dst = &Aw[((size_t)b * Sn + qs) * Dn + h * DHn + c];
        dst[0]  = acc[0][r] * inv;
        dst[16] = acc[1][r] * inv;
        dst[32] = acc[2][r] * inv;
        dst[48] = acc[3][r] * inv;
    }
}

// ---------------------------------------------------------------------------
// LayerNorm over D=1024 per (b,s) row; f32 output.
// ---------------------------------------------------------------------------
__global__ __launch_bounds__(256) void ln_kernel(
    const float* __restrict__ Aw, const float* __restrict__ gamma,
    const float* __restrict__ beta, float* __restrict__ out)
{
    const int row = blockIdx.x;
    const int tid = threadIdx.x;
    const int d0 = tid * 4;
    const float4 x = *(const float4*)&Aw[(size_t)row * Dn + d0];
    float sum = x.x + x.y + x.z + x.w;
    float sq = x.x * x.x + x.y * x.y + x.z * x.z + x.w * x.w;
    for (int off = 32; off; off >>= 1) {
        sum += __shfl_xor(sum, off);
        sq += __shfl_xor(sq, off);
    }
    __shared__ float red[8];
    const int lane = tid & 63, wave = tid >> 6;
    if (lane == 0) { red[wave] = sum; red[wave + 4] = sq; }
    __syncthreads();
    if (tid == 0) {
        red[0] = red[0] + red[1] + red[2] + red[3];
        red[4] = red[4] + red[5] + red[6] + red[7];
    }
    __syncthreads();
    sum = red[0]; sq = red[4];
    const float mu = sum * (1.0f / Dn);
    const float var = sq * (1.0f / Dn) - mu * mu;
    const float rs = rsqrtf(var + 1e-5f);

    const float4 gv = *(const float4*)&gamma[d0];
    const float4 bv = *(const float4*)&beta[d0];
    float4 ov;
    ov.x = (x.x - mu) * rs * gv.x + bv.x;
    ov.y = (x.y - mu) * rs * gv.y + bv.y;
    ov.z = (x.z - mu) * rs * gv.z + bv.z;
    ov.w = (x.w - mu) * rs * gv.w + bv.w;
    *(float4*)&out[(size_t)row * Dn + d0] = ov;
}

extern "C" void kernel_launch(void* const* d_in, const int* in_sizes, int n_in,
                              void* d_out, int out_size, void* d_ws, size_t ws_size,
                              hipStream_t stream)
{
    const float* x_qk = (const float*)d_in[0];
    const float* x_v  = (const float*)d_in[1];
    const float* W_qk = (const float*)d_in[2];
    const float* b_qk = (const float*)d_in[3];
    const float* W_v  = (const float*)d_in[4];
    const float* b_v  = (const float*)d_in[5];
    const float* g    = (const float*)d_in[6];
    const float* be   = (const float*)d_in[7];

    char* ws = (char*)d_ws;
    ushort* Qw    = (ushort*)(ws);                  //  8 MB bf16 (b,h,s,dh)
    ushort* Kw    = (ushort*)(ws + (8u  << 20));    //  8 MB bf16 (b,h,s,dh)
    ushort* Vtw   = (ushort*)(ws + (16u << 20));    //  8 MB bf16 (b,h,dh,s)
    float*  Aw    = (float*) (ws + (24u << 20));    // 16 MB f32  (b,s,D)
    ushort* xqkB  = (ushort*)(ws + (40u << 20));    //  8 MB bf16 [M][K]
    ushort* xvB   = (ushort*)(ws + (48u << 20));    //  8 MB bf16 [M][K]
    ushort* WqkT  = (ushort*)(ws + (56u << 20));    //  4 MB bf16 [2048][1024]
    ushort* WvT   = (ushort*)(ws + (60u << 20));    //  2 MB bf16 [1024][1024]
    float*  ctab  = (float*) (ws + (62u << 20));    // 256 KB
    float*  stab  = (float*) (ws + (62u << 20) + (256u << 10));

    rope_tab<<<256, 256, 0, stream>>>(ctab, stab);
    cvt_bf16<<<2048, 256, 0, stream>>>(x_qk, xqkB);
    cvt_bf16<<<2048, 256, 0, stream>>>(x_v, xvB);
    transpose_bf16<<<dim3(64, 32), dim3(32, 8), 0, stream>>>(W_qk, WqkT, Kd, 2048);
    transpose_bf16<<<dim3(32, 32), dim3(32, 8), 0, stream>>>(W_v, WvT, Kd, 1024);

    gemm_mfma<0><<<dim3(16, 32), 256, 0, stream>>>(
        xqkB, WqkT, b_qk, ctab, stab, Qw, Kw);
    gemm_mfma<1><<<dim3(8, 32), 256, 0, stream>>>(
        xvB, WvT, b_v, ctab, stab, Vtw, nullptr);

    attn_mfma<<<dim3(32, 32), 256, 0, stream>>>(Qw, Kw, Vtw, Aw);
    ln_kernel<<<Bn * Sn, 256, 0, stream>>>(Aw, g, be, (float*)d_out);
}

// Round 8
// 195.111 us; speedup vs baseline: 2.1484x; 1.1651x over previous
//
#include <hip/hip_runtime.h>
#include <hip/hip_bf16.h>

// B=2, S=2048, D=1024, H=16, DH=64. f32 in/out; bf16 intermediates for MFMA.
#define Bn 2
#define Sn 2048
#define Dn 1024
#define Hn 16
#define DHn 64
#define Kd 1024
#define Mn (Bn * Sn)
#define LN10K 9.210340371976184f

typedef __attribute__((ext_vector_type(8))) short bf16x8;  // MFMA A/B frag
typedef __attribute__((ext_vector_type(4))) float f32x4;   // MFMA C/D frag

static __device__ __forceinline__ ushort f2bf(float f) {
    uint u = __float_as_uint(f);
    u += 0x7fff + ((u >> 16) & 1);   // round-nearest-even
    return (ushort)(u >> 16);
}
// packed f32x2 -> bf16x2 (RNE), lo = a, hi = b
static __device__ __forceinline__ uint cvtpk(float a, float b) {
    uint r;
    asm("v_cvt_pk_bf16_f32 %0, %1, %2" : "=v"(r) : "v"(a), "v"(b));
    return r;
}

#define MFMA16(a, b, c) __builtin_amdgcn_mfma_f32_16x16x32_bf16((a), (b), (c), 0, 0, 0)

// async global->LDS, 16B per lane. LDS dest is wave-uniform base + lane*16.
static __device__ __forceinline__ void gload16(const ushort* g, ushort* l) {
    __builtin_amdgcn_global_load_lds(
        (const __attribute__((address_space(1))) void*)g,
        (__attribute__((address_space(3))) void*)l, 16, 0, 0);
}

// XOR swizzle for [rows][128B] LDS tiles (16B granules).
static __device__ __forceinline__ int swz(int row, int col16) {
    return row * 128 + (((col16) * 16) ^ ((row & 7) << 4));
}

// ---------------------------------------------------------------------------
__global__ __launch_bounds__(256) void rope_tab(float* __restrict__ ct,
                                                float* __restrict__ st)
{
    const int idx = blockIdx.x * 256 + threadIdx.x;
    const int s = idx >> 5, fe = idx & 31;
    const float f = expf(-LN10K * (float)fe / 32.0f);
    const float a = (float)s * f;
    ct[idx] = cosf(a);
    st[idx] = sinf(a);
}

__global__ __launch_bounds__(256) void cvt_bf16(const float* __restrict__ in,
                                                ushort* __restrict__ out)
{
    const size_t i = ((size_t)blockIdx.x * 256 + threadIdx.x) * 8;
    const float4 a = *(const float4*)(in + i);
    const float4 b = *(const float4*)(in + i + 4);
    ushort4 lo = make_ushort4(f2bf(a.x), f2bf(a.y), f2bf(a.z), f2bf(a.w));
    ushort4 hi = make_ushort4(f2bf(b.x), f2bf(b.y), f2bf(b.z), f2bf(b.w));
    *(ushort4*)(out + i) = lo;
    *(ushort4*)(out + i + 4) = hi;
}

__global__ __launch_bounds__(256) void transpose_bf16(
    const float* __restrict__ in, ushort* __restrict__ out, int R, int C)
{
    __shared__ ushort t[32][33];
    const int n0 = blockIdx.x * 32, k0 = blockIdx.y * 32;
    const int x = threadIdx.x, y = threadIdx.y;
#pragma unroll
    for (int i = 0; i < 4; ++i)
        t[y + 8 * i][x] = f2bf(in[(size_t)(k0 + y + 8 * i) * C + n0 + x]);
    __syncthreads();
#pragma unroll
    for (int i = 0; i < 4; ++i)
        out[(size_t)(n0 + y + 8 * i) * R + k0 + x] = t[x][y + 8 * i];
}

// ---------------------------------------------------------------------------
// MFMA GEMM, m97-style: 128x128 tile, BK=64, single-buffered LDS staged via
// global_load_lds w=16 (linear dest, inverse-swizzled source, swizzled read).
// 4 waves, each 64x64 output. 2 barriers per K-step.
// ---------------------------------------------------------------------------
template <int MODE>
__global__ __launch_bounds__(256) void gemm_mfma(
    const ushort* __restrict__ A, const ushort* __restrict__ Bt,
    const float* __restrict__ bias, const float* __restrict__ ctab,
    const float* __restrict__ stab, ushort* __restrict__ o0,
    ushort* __restrict__ o1)
{
    __shared__ ushort Asm[128 * 64];   // [row][k] bf16, 128B rows, swizzled
    __shared__ ushort Bsm[128 * 64];

    const int tid = threadIdx.x;
    const int lane = tid & 63, w = tid >> 6;
    const int g = lane >> 4, c = lane & 15;
    const int mbase = blockIdx.y * 128;
    const int nbase = blockIdx.x * 128;
    const int wm = (w >> 1) * 64, wn = (w & 1) * 64;

    f32x4 acc[4][4];
#pragma unroll
    for (int mf = 0; mf < 4; ++mf)
#pragma unroll
        for (int nf = 0; nf < 4; ++nf)
            acc[mf][nf] = (f32x4){0.f, 0.f, 0.f, 0.f};

    // staging map: chunk i = j*256 + w*64 + lane covers (row = i>>3, c16 = i&7);
    // source chunk is c16 ^ (row&7) so a linear DMA write + swizzled read agree.
    const int sbase = w * 64 + lane;

    for (int k0 = 0; k0 < Kd; k0 += 64) {
#pragma unroll
        for (int j = 0; j < 4; ++j) {
            const int i = j * 256 + sbase;
            const int row = i >> 3, c16 = i & 7;
            const int kc = (c16 ^ (row & 7)) * 8;
            gload16(A + (size_t)(mbase + row) * Kd + k0 + kc,
                    &Asm[(size_t)(j * 256 + w * 64) * 8]);
            gload16(Bt + (size_t)(nbase + row) * Kd + k0 + kc,
                    &Bsm[(size_t)(j * 256 + w * 64) * 8]);
        }
        __syncthreads();   // drains vmcnt (compiler) + staging visible

#pragma unroll
        for (int ks = 0; ks < 2; ++ks) {
            bf16x8 af[4], bfr[4];
#pragma unroll
            for (int mf = 0; mf < 4; ++mf) {
                const int row = wm + mf * 16 + c;
                af[mf] = *(const bf16x8*)((const char*)Asm + swz(row, ks * 4 + g));
            }
#pragma unroll
            for (int nf = 0; nf < 4; ++nf) {
                const int row = wn + nf * 16 + c;
                bfr[nf] = *(const bf16x8*)((const char*)Bsm + swz(row, ks * 4 + g));
            }
#pragma unroll
            for (int mf = 0; mf < 4; ++mf)
#pragma unroll
                for (int nf = 0; nf < 4; ++nf)
                    acc[mf][nf] = MFMA16(af[mf], bfr[nf], acc[mf][nf]);
        }
        __syncthreads();   // compute done before next stage overwrites
    }

#pragma unroll
    for (int nf = 0; nf < 4; ++nf) {
        const int col = nbase + wn + nf * 16 + c;
        const float bs = bias[col];
        if (MODE == 0) {
            const int dh = col & 63, h = (col >> 6) & 15, isK = col >> 10;
            ushort* dst = isK ? o1 : o0;
            const float sc = isK ? 1.0f : 0.125f;   // fold 1/sqrt(64) into Q
            const float* cr = ctab + (dh & 31);
            const float* sr = stab + (dh & 31);
#pragma unroll
            for (int mf = 0; mf < 4; ++mf) {
#pragma unroll
                for (int r = 0; r < 4; ++r) {
                    const int row = mbase + wm + mf * 16 + g * 4 + r;
                    const int s = row & 2047, b = row >> 11;
                    const float v = acc[mf][nf][r] + bs;
                    const float p = __shfl_xor(v, 1);
                    const float cs = cr[s * 32], sn = sr[s * 32];
                    const float ov = (c & 1) ? v * cs + p * sn
                                             : v * cs - p * sn;
                    dst[(((size_t)(b * Hn + h)) * Sn + s) * DHn + dh] =
                        f2bf(ov * sc);
                }
            }
        } else {
            const int h = col >> 6, dh = col & 63;
#pragma unroll
            for (int mf = 0; mf < 4; ++mf) {
#pragma unroll
                for (int r = 0; r < 4; ++r) {
                    const int row = mbase + wm + mf * 16 + g * 4 + r;
                    const int s = row & 2047, b = row >> 11;
                    const float v = acc[mf][nf][r] + bs;
                    o0[(((size_t)(b * Hn + h)) * DHn + dh) * Sn + s] = f2bf(v);
                }
            }
        }
    }
}

// ---------------------------------------------------------------------------
// MFMA flash attention (round 7 structure + T5 setprio around MFMA clusters).
// ---------------------------------------------------------------------------
__global__ __launch_bounds__(256) void attn_mfma(
    const ushort* __restrict__ Qg, const ushort* __restrict__ Kg,
    const ushort* __restrict__ Vt, float* __restrict__ Aw)
{
    __shared__ char Kt[2][8192];        // [64 kv][64 d] bf16, swizzled
    __shared__ char Vtile[2][8192];     // [64 dh][64 u]  bf16, swizzled, pi-permuted
    __shared__ ushort Pw[4][16][72];    // per-wave P [q][u], 144B rows

    const int tid = threadIdx.x;
    const int lane = tid & 63, w = tid >> 6;
    const int g = lane >> 4, c = lane & 15;
    const int bh = blockIdx.y;
    const int b = bh >> 4, h = bh & 15;
    const int q0 = blockIdx.x * 64 + w * 16;

    const size_t qrow = ((size_t)bh * Sn + q0 + c) * DHn;
    const bf16x8 qa0 = *(const bf16x8*)&Qg[qrow + g * 8];
    const bf16x8 qa1 = *(const bf16x8*)&Qg[qrow + 32 + g * 8];

    const ushort* Kb = Kg + (size_t)bh * Sn * DHn;
    const ushort* Vb = Vt + (size_t)bh * DHn * Sn;

    const int srow = tid >> 3;          // 0..31
    const int scol = tid & 7;           // 0..7

    auto stV = [&](char* dst, const bf16x8 v, int row) {
#pragma unroll
        for (int i = 0; i < 8; ++i) {
            const int kvl = scol * 8 + i;                 // tile-local kv
            const int u = 4 * (kvl & 15) + (kvl >> 4);
            const int byte = row * 128 + ((2 * u) ^ ((row & 7) << 4));
            *(ushort*)&dst[byte] = (ushort)v[i];
        }
    };

    {
        const bf16x8 k0 = *(const bf16x8*)&Kb[(size_t)srow * DHn + scol * 8];
        const bf16x8 k1 = *(const bf16x8*)&Kb[(size_t)(srow + 32) * DHn + scol * 8];
        const bf16x8 v0 = *(const bf16x8*)&Vb[(size_t)srow * Sn + scol * 8];
        const bf16x8 v1 = *(const bf16x8*)&Vb[(size_t)(srow + 32) * Sn + scol * 8];
        *(bf16x8*)&Kt[0][swz(srow, scol)] = k0;
        *(bf16x8*)&Kt[0][swz(srow + 32, scol)] = k1;
        stV(Vtile[0], v0, srow);
        stV(Vtile[0], v1, srow + 32);
    }
    __syncthreads();

    f32x4 acc[4];
#pragma unroll
    for (int nf = 0; nf < 4; ++nf) acc[nf] = (f32x4){0.f, 0.f, 0.f, 0.f};
    float m[4] = {-1e30f, -1e30f, -1e30f, -1e30f};
    float lp[4] = {0.f, 0.f, 0.f, 0.f};   // per-lane partial denominators

    for (int t = 0; t < Sn / 64; ++t) {
        const int cur = t & 1;
        const bool pf = (t + 1 < Sn / 64);

        bf16x8 kr0, kr1, vr0, vr1;
        if (pf) {
            const int kb2 = (t + 1) * 64;
            kr0 = *(const bf16x8*)&Kb[(size_t)(kb2 + srow) * DHn + scol * 8];
            kr1 = *(const bf16x8*)&Kb[(size_t)(kb2 + srow + 32) * DHn + scol * 8];
            vr0 = *(const bf16x8*)&Vb[(size_t)srow * Sn + kb2 + scol * 8];
            vr1 = *(const bf16x8*)&Vb[(size_t)(srow + 32) * Sn + kb2 + scol * 8];
            asm volatile("" ::: "memory");   // pin load issue before compute
        }

        // ---- QK^T ----
        bf16x8 kf[4][2];
#pragma unroll
        for (int sub = 0; sub < 4; ++sub) {
            kf[sub][0] = *(const bf16x8*)&Kt[cur][swz(sub * 16 + c, g)];
            kf[sub][1] = *(const bf16x8*)&Kt[cur][swz(sub * 16 + c, 4 + g)];
        }
        const f32x4 z = {0.f, 0.f, 0.f, 0.f};
        f32x4 C[4];
        __builtin_amdgcn_s_setprio(1);
#pragma unroll
        for (int sub = 0; sub < 4; ++sub) {
            C[sub] = MFMA16(qa0, kf[sub][0], z);
            C[sub] = MFMA16(qa1, kf[sub][1], C[sub]);
        }
        __builtin_amdgcn_s_setprio(0);

        // ---- row maxima ----
        float pmax[4];
        int need = 0;
#pragma unroll
        for (int r = 0; r < 4; ++r) {
            float v = fmaxf(fmaxf(C[0][r], C[1][r]), fmaxf(C[2][r], C[3][r]));
            v = fmaxf(v, __shfl_xor(v, 1));
            v = fmaxf(v, __shfl_xor(v, 2));
            v = fmaxf(v, __shfl_xor(v, 4));
            v = fmaxf(v, __shfl_xor(v, 8));
            pmax[r] = v;
            need |= (v > m[r] + 8.0f);
        }
        if (__any(need)) {
#pragma unroll
            for (int r = 0; r < 4; ++r) {
                const float mn = fmaxf(m[r], pmax[r]);
                const float a = __expf(m[r] - mn);
                m[r] = mn;
                lp[r] *= a;
#pragma unroll
                for (int nf = 0; nf < 4; ++nf) acc[nf][r] *= a;
            }
        }

        // ---- exp + P write (pi layout: lane's 4 values contiguous) ----
#pragma unroll
        for (int r = 0; r < 4; ++r) {
            const float e0 = __expf(C[0][r] - m[r]);
            const float e1 = __expf(C[1][r] - m[r]);
            const float e2 = __expf(C[2][r] - m[r]);
            const float e3 = __expf(C[3][r] - m[r]);
            lp[r] += (e0 + e1) + (e2 + e3);
            uint2 pk;
            pk.x = cvtpk(e0, e1);
            pk.y = cvtpk(e2, e3);
            *(uint2*)&Pw[w][g * 4 + r][4 * c] = pk;
        }

        // ---- PV ----
        const bf16x8 pa0 = *(const bf16x8*)&Pw[w][c][g * 8];
        const bf16x8 pa1 = *(const bf16x8*)&Pw[w][c][32 + g * 8];
        __builtin_amdgcn_s_setprio(1);
#pragma unroll
        for (int nf = 0; nf < 4; ++nf) {
            const bf16x8 vfa = *(const bf16x8*)&Vtile[cur][swz(nf * 16 + c, g)];
            const bf16x8 vfb = *(const bf16x8*)&Vtile[cur][swz(nf * 16 + c, 4 + g)];
            acc[nf] = MFMA16(pa0, vfa, acc[nf]);
            acc[nf] = MFMA16(pa1, vfb, acc[nf]);
        }
        __builtin_amdgcn_s_setprio(0);

        __syncthreads();   // #1: all reads of buf[cur] done
        if (pf) {
            const int nxt = cur ^ 1;
            *(bf16x8*)&Kt[nxt][swz(srow, scol)] = kr0;
            *(bf16x8*)&Kt[nxt][swz(srow + 32, scol)] = kr1;
            stV(Vtile[nxt], vr0, srow);
            stV(Vtile[nxt], vr1, srow + 32);
        }
        __syncthreads();   // #2: staged writes visible
    }

    // ---- epilogue: reduce per-lane partials, divide, store ----
#pragma unroll
    for (int r = 0; r < 4; ++r) {
        float lv = lp[r];
        lv += __shfl_xor(lv, 1);
        lv += __shfl_xor(lv, 2);
        lv += __shfl_xor(lv, 4);
        lv += __shfl_xor(lv, 8);
        const float inv = 1.0f / lv;
        const int qs = q0 + g * 4 + r;
        float* dst = &Aw[((size_t)b * Sn + qs) * Dn + h * DHn + c];
        dst[0]  = acc[0][r] * inv;
        dst[16] = acc[1][r] * inv;
        dst[32] = acc[2][r] * inv;
        dst[48] = acc[3][r] * inv;
    }
}

// ---------------------------------------------------------------------------
// LayerNorm over D=1024 per (b,s) row; f32 output.
// ---------------------------------------------------------------------------
__global__ __launch_bounds__(256) void ln_kernel(
    const float* __restrict__ Aw, const float* __restrict__ gamma,
    const float* __restrict__ beta, float* __restrict__ out)
{
    const int row = blockIdx.x;
    const int tid = threadIdx.x;
    const int d0 = tid * 4;
    const float4 x = *(const float4*)&Aw[(size_t)row * Dn + d0];
    float sum = x.x + x.y + x.z + x.w;
    float sq = x.x * x.x + x.y * x.y + x.z * x.z + x.w * x.w;
    for (int off = 32; off; off >>= 1) {
        sum += __shfl_xor(sum, off);
        sq += __shfl_xor(sq, off);
    }
    __shared__ float red[8];
    const int lane = tid & 63, wave = tid >> 6;
    if (lane == 0) { red[wave] = sum; red[wave + 4] = sq; }
    __syncthreads();
    if (tid == 0) {
        red[0] = red[0] + red[1] + red[2] + red[3];
        red[4] = red[4] + red[5] + red[6] + red[7];
    }
    __syncthreads();
    sum = red[0]; sq = red[4];
    const float mu = sum * (1.0f / Dn);
    const float var = sq * (1.0f / Dn) - mu * mu;
    const float rs = rsqrtf(var + 1e-5f);

    const float4 gv = *(const float4*)&gamma[d0];
    const float4 bv = *(const float4*)&beta[d0];
    float4 ov;
    ov.x = (x.x - mu) * rs * gv.x + bv.x;
    ov.y = (x.y - mu) * rs * gv.y + bv.y;
    ov.z = (x.z - mu) * rs * gv.z + bv.z;
    ov.w = (x.w - mu) * rs * gv.w + bv.w;
    *(float4*)&out[(size_t)row * Dn + d0] = ov;
}

extern "C" void kernel_launch(void* const* d_in, const int* in_sizes, int n_in,
                              void* d_out, int out_size, void* d_ws, size_t ws_size,
                              hipStream_t stream)
{
    const float* x_qk = (const float*)d_in[0];
    const float* x_v  = (const float*)d_in[1];
    const float* W_qk = (const float*)d_in[2];
    const float* b_qk = (const float*)d_in[3];
    const float* W_v  = (const float*)d_in[4];
    const float* b_v  = (const float*)d_in[5];
    const float* g    = (const float*)d_in[6];
    const float* be   = (const float*)d_in[7];

    char* ws = (char*)d_ws;
    ushort* Qw    = (ushort*)(ws);                  //  8 MB bf16 (b,h,s,dh)
    ushort* Kw    = (ushort*)(ws + (8u  << 20));    //  8 MB bf16 (b,h,s,dh)
    ushort* Vtw   = (ushort*)(ws + (16u << 20));    //  8 MB bf16 (b,h,dh,s)
    float*  Aw    = (float*) (ws + (24u << 20));    // 16 MB f32  (b,s,D)
    ushort* xqkB  = (ushort*)(ws + (40u << 20));    //  8 MB bf16 [M][K]
    ushort* xvB   = (ushort*)(ws + (48u << 20));    //  8 MB bf16 [M][K]
    ushort* WqkT  = (ushort*)(ws + (56u << 20));    //  4 MB bf16 [2048][1024]
    ushort* WvT   = (ushort*)(ws + (60u << 20));    //  2 MB bf16 [1024][1024]
    float*  ctab  = (float*) (ws + (62u << 20));    // 256 KB
    float*  stab  = (float*) (ws + (62u << 20) + (256u << 10));

    rope_tab<<<256, 256, 0, stream>>>(ctab, stab);
    cvt_bf16<<<2048, 256, 0, stream>>>(x_qk, xqkB);
    cvt_bf16<<<2048, 256, 0, stream>>>(x_v, xvB);
    transpose_bf16<<<dim3(64, 32), dim3(32, 8), 0, stream>>>(W_qk, WqkT, Kd, 2048);
    transpose_bf16<<<dim3(32, 32), dim3(32, 8), 0, stream>>>(W_v, WvT, Kd, 1024);

    gemm_mfma<0><<<dim3(16, 32), 256, 0, stream>>>(
        xqkB, WqkT, b_qk, ctab, stab, Qw, Kw);
    gemm_mfma<1><<<dim3(8, 32), 256, 0, stream>>>(
        xvB, WvT, b_v, ctab, stab, Vtw, nullptr);

    attn_mfma<<<dim3(32, 32), 256, 0, stream>>>(Qw, Kw, Vtw, Aw);
    ln_kernel<<<Bn * Sn, 256, 0, stream>>>(Aw, g, be, (float*)d_out);
}

// Round 9
// 171.190 us; speedup vs baseline: 2.4487x; 1.1397x over previous
//
#include <hip/hip_runtime.h>
#include <hip/hip_bf16.h>

// B=2, S=2048, D=1024, H=16, DH=64. f32 in/out; bf16 intermediates for MFMA.
#define Bn 2
#define Sn 2048
#define Dn 1024
#define Hn 16
#define DHn 64
#define Kd 1024
#define Mn (Bn * Sn)
#define LN10K 9.210340371976184f

typedef __attribute__((ext_vector_type(8))) short bf16x8;  // MFMA A/B frag
typedef __attribute__((ext_vector_type(4))) float f32x4;   // MFMA C/D frag

static __device__ __forceinline__ ushort f2bf(float f) {
    uint u = __float_as_uint(f);
    u += 0x7fff + ((u >> 16) & 1);   // round-nearest-even
    return (ushort)(u >> 16);
}
// packed f32x2 -> bf16x2 (RNE), lo = a, hi = b
static __device__ __forceinline__ uint cvtpk(float a, float b) {
    uint r;
    asm("v_cvt_pk_bf16_f32 %0, %1, %2" : "=v"(r) : "v"(a), "v"(b));
    return r;
}

#define MFMA16(a, b, c) __builtin_amdgcn_mfma_f32_16x16x32_bf16((a), (b), (c), 0, 0, 0)

// async global->LDS, 16B per lane. LDS dest is wave-uniform base + lane*16.
static __device__ __forceinline__ void gload16(const ushort* g, ushort* l) {
    __builtin_amdgcn_global_load_lds(
        (const __attribute__((address_space(1))) void*)g,
        (__attribute__((address_space(3))) void*)l, 16, 0, 0);
}

// XOR swizzle for [rows][128B] LDS tiles (16B granules).
static __device__ __forceinline__ int swz(int row, int col16) {
    return row * 128 + (((col16) * 16) ^ ((row & 7) << 4));
}

// ---------------------------------------------------------------------------
__global__ __launch_bounds__(256) void rope_tab(float* __restrict__ ct,
                                                float* __restrict__ st)
{
    const int idx = blockIdx.x * 256 + threadIdx.x;
    const int s = idx >> 5, fe = idx & 31;
    const float f = expf(-LN10K * (float)fe / 32.0f);
    const float a = (float)s * f;
    ct[idx] = cosf(a);
    st[idx] = sinf(a);
}

__global__ __launch_bounds__(256) void cvt_bf16(const float* __restrict__ in,
                                                ushort* __restrict__ out)
{
    const size_t i = ((size_t)blockIdx.x * 256 + threadIdx.x) * 8;
    const float4 a = *(const float4*)(in + i);
    const float4 b = *(const float4*)(in + i + 4);
    ushort4 lo = make_ushort4(f2bf(a.x), f2bf(a.y), f2bf(a.z), f2bf(a.w));
    ushort4 hi = make_ushort4(f2bf(b.x), f2bf(b.y), f2bf(b.z), f2bf(b.w));
    *(ushort4*)(out + i) = lo;
    *(ushort4*)(out + i + 4) = hi;
}

__global__ __launch_bounds__(256) void transpose_bf16(
    const float* __restrict__ in, ushort* __restrict__ out, int R, int C)
{
    __shared__ ushort t[32][33];
    const int n0 = blockIdx.x * 32, k0 = blockIdx.y * 32;
    const int x = threadIdx.x, y = threadIdx.y;
#pragma unroll
    for (int i = 0; i < 4; ++i)
        t[y + 8 * i][x] = f2bf(in[(size_t)(k0 + y + 8 * i) * C + n0 + x]);
    __syncthreads();
#pragma unroll
    for (int i = 0; i < 4; ++i)
        out[(size_t)(n0 + y + 8 * i) * R + k0 + x] = t[x][y + 8 * i];
}

// ---------------------------------------------------------------------------
// MFMA GEMM, m97-style (as round 8, unchanged).
// ---------------------------------------------------------------------------
template <int MODE>
__global__ __launch_bounds__(256) void gemm_mfma(
    const ushort* __restrict__ A, const ushort* __restrict__ Bt,
    const float* __restrict__ bias, const float* __restrict__ ctab,
    const float* __restrict__ stab, ushort* __restrict__ o0,
    ushort* __restrict__ o1)
{
    __shared__ ushort Asm[128 * 64];   // [row][k] bf16, 128B rows, swizzled
    __shared__ ushort Bsm[128 * 64];

    const int tid = threadIdx.x;
    const int lane = tid & 63, w = tid >> 6;
    const int g = lane >> 4, c = lane & 15;
    const int mbase = blockIdx.y * 128;
    const int nbase = blockIdx.x * 128;
    const int wm = (w >> 1) * 64, wn = (w & 1) * 64;

    f32x4 acc[4][4];
#pragma unroll
    for (int mf = 0; mf < 4; ++mf)
#pragma unroll
        for (int nf = 0; nf < 4; ++nf)
            acc[mf][nf] = (f32x4){0.f, 0.f, 0.f, 0.f};

    const int sbase = w * 64 + lane;

    for (int k0 = 0; k0 < Kd; k0 += 64) {
#pragma unroll
        for (int j = 0; j < 4; ++j) {
            const int i = j * 256 + sbase;
            const int row = i >> 3, c16 = i & 7;
            const int kc = (c16 ^ (row & 7)) * 8;
            gload16(A + (size_t)(mbase + row) * Kd + k0 + kc,
                    &Asm[(size_t)(j * 256 + w * 64) * 8]);
            gload16(Bt + (size_t)(nbase + row) * Kd + k0 + kc,
                    &Bsm[(size_t)(j * 256 + w * 64) * 8]);
        }
        __syncthreads();

#pragma unroll
        for (int ks = 0; ks < 2; ++ks) {
            bf16x8 af[4], bfr[4];
#pragma unroll
            for (int mf = 0; mf < 4; ++mf) {
                const int row = wm + mf * 16 + c;
                af[mf] = *(const bf16x8*)((const char*)Asm + swz(row, ks * 4 + g));
            }
#pragma unroll
            for (int nf = 0; nf < 4; ++nf) {
                const int row = wn + nf * 16 + c;
                bfr[nf] = *(const bf16x8*)((const char*)Bsm + swz(row, ks * 4 + g));
            }
#pragma unroll
            for (int mf = 0; mf < 4; ++mf)
#pragma unroll
                for (int nf = 0; nf < 4; ++nf)
                    acc[mf][nf] = MFMA16(af[mf], bfr[nf], acc[mf][nf]);
        }
        __syncthreads();
    }

#pragma unroll
    for (int nf = 0; nf < 4; ++nf) {
        const int col = nbase + wn + nf * 16 + c;
        const float bs = bias[col];
        if (MODE == 0) {
            const int dh = col & 63, h = (col >> 6) & 15, isK = col >> 10;
            ushort* dst = isK ? o1 : o0;
            const float sc = isK ? 1.0f : 0.125f;   // fold 1/sqrt(64) into Q
            const float* cr = ctab + (dh & 31);
            const float* sr = stab + (dh & 31);
#pragma unroll
            for (int mf = 0; mf < 4; ++mf) {
#pragma unroll
                for (int r = 0; r < 4; ++r) {
                    const int row = mbase + wm + mf * 16 + g * 4 + r;
                    const int s = row & 2047, b = row >> 11;
                    const float v = acc[mf][nf][r] + bs;
                    const float p = __shfl_xor(v, 1);
                    const float cs = cr[s * 32], sn = sr[s * 32];
                    const float ov = (c & 1) ? v * cs + p * sn
                                             : v * cs - p * sn;
                    dst[(((size_t)(b * Hn + h)) * Sn + s) * DHn + dh] =
                        f2bf(ov * sc);
                }
            }
        } else {
            const int h = col >> 6, dh = col & 63;
#pragma unroll
            for (int mf = 0; mf < 4; ++mf) {
#pragma unroll
                for (int r = 0; r < 4; ++r) {
                    const int row = mbase + wm + mf * 16 + g * 4 + r;
                    const int s = row & 2047, b = row >> 11;
                    const float v = acc[mf][nf][r] + bs;
                    o0[(((size_t)(b * Hn + h)) * DHn + dh) * Sn + s] = f2bf(v);
                }
            }
        }
    }
}

// ---------------------------------------------------------------------------
// MFMA flash attention, round 9: swapped QK^T (C = S^T, q = lane&15) ->
// in-register softmax (scalar m/lp per lane, in-reg max tree + 2 shfl_xor);
// P rebuilt as PV A-frag via 8 cvt_pk + 16 shfl + 8 selects (no P LDS);
// K AND V staged linearly via global_load_lds w=16 with xor-source (rule 21);
// one barrier per KV tile. LDS 32KB (was 41KB).
// ---------------------------------------------------------------------------
__global__ __launch_bounds__(256) void attn_mfma(
    const ushort* __restrict__ Qg, const ushort* __restrict__ Kg,
    const ushort* __restrict__ Vtg, float* __restrict__ Aw)
{
    __shared__ char Kt[2][8192];   // [64 kv][64 d] bf16, swizzled
    __shared__ char Vt[2][8192];   // [64 dh][64 kv] bf16, swizzled

    const int tid = threadIdx.x;
    const int lane = tid & 63, w = tid >> 6;
    const int g = lane >> 4, c = lane & 15;
    const int bh = blockIdx.y;
    const int b = bh >> 4, h = bh & 15;
    const int q0 = blockIdx.x * 64 + w * 16;

    // Q fragments (B-operand): lane holds Q[q=c][d = half*32 + g*8 + j]
    const size_t qrow = ((size_t)bh * Sn + q0 + c) * DHn;
    const bf16x8 qa0 = *(const bf16x8*)&Qg[qrow + g * 8];
    const bf16x8 qa1 = *(const bf16x8*)&Qg[qrow + 32 + g * 8];

    const ushort* Kb = Kg + (size_t)bh * Sn * DHn;
    const ushort* Vb = Vtg + (size_t)bh * DHn * Sn;

    // stage one 64x64 bf16 tile pair: 512 chunks each, 2 per thread per tensor
    auto stage = [&](int buf, int kb) {
#pragma unroll
        for (int j = 0; j < 2; ++j) {
            const int i = j * 256 + w * 64 + lane;
            const int row = i >> 3, c16 = i & 7;
            const int kc = (c16 ^ (row & 7)) * 8;
            gload16(Kb + (size_t)(kb + row) * DHn + kc,
                    (ushort*)&Kt[buf][(j * 256 + w * 64) * 16]);
            gload16(Vb + (size_t)row * Sn + kb + kc,
                    (ushort*)&Vt[buf][(j * 256 + w * 64) * 16]);
        }
    };

    stage(0, 0);
    __syncthreads();

    f32x4 acc[4];
#pragma unroll
    for (int nf = 0; nf < 4; ++nf) acc[nf] = (f32x4){0.f, 0.f, 0.f, 0.f};
    float m = -1e30f, lp = 0.f;

    for (int t = 0; t < Sn / 64; ++t) {
        const int cur = t & 1;
        if (t + 1 < Sn / 64) stage(cur ^ 1, (t + 1) * 64);

        // ---- QK^T swapped: C[sub][r] = S[q=c][kv = sub*16 + g*4 + r] ----
        const f32x4 z = {0.f, 0.f, 0.f, 0.f};
        f32x4 C[4];
        __builtin_amdgcn_s_setprio(1);
#pragma unroll
        for (int sub = 0; sub < 4; ++sub) {
            const bf16x8 k0 = *(const bf16x8*)&Kt[cur][swz(sub * 16 + c, g)];
            const bf16x8 k1 = *(const bf16x8*)&Kt[cur][swz(sub * 16 + c, 4 + g)];
            C[sub] = MFMA16(k0, qa0, z);
            C[sub] = MFMA16(k1, qa1, C[sub]);
        }
        __builtin_amdgcn_s_setprio(0);

        // ---- row max: in-register tree + 2 shfl_xor across g-groups ----
        float pmax = fmaxf(fmaxf(C[0][0], C[0][1]), fmaxf(C[0][2], C[0][3]));
        pmax = fmaxf(pmax, fmaxf(fmaxf(C[1][0], C[1][1]), fmaxf(C[1][2], C[1][3])));
        pmax = fmaxf(pmax, fmaxf(fmaxf(C[2][0], C[2][1]), fmaxf(C[2][2], C[2][3])));
        pmax = fmaxf(pmax, fmaxf(fmaxf(C[3][0], C[3][1]), fmaxf(C[3][2], C[3][3])));
        pmax = fmaxf(pmax, __shfl_xor(pmax, 16));
        pmax = fmaxf(pmax, __shfl_xor(pmax, 32));

        // ---- defer-max rescale (rare) ----
        if (__any(pmax > m + 8.0f)) {
            const float mn = fmaxf(m, pmax);
            const float a = __expf(m - mn);
            m = mn;
            lp *= a;
            float ar[4];
#pragma unroll
            for (int r = 0; r < 4; ++r) ar[r] = __shfl(a, g * 4 + r);
#pragma unroll
            for (int nf = 0; nf < 4; ++nf)
#pragma unroll
                for (int r = 0; r < 4; ++r) acc[nf][r] *= ar[r];
        }

        // ---- exp + pack to bf16 pairs (kv order) ----
        uint pk[4][2];
        float s0 = 0.f, s1 = 0.f;
#pragma unroll
        for (int sub = 0; sub < 4; ++sub) {
            const float e0 = __expf(C[sub][0] - m);
            const float e1 = __expf(C[sub][1] - m);
            const float e2 = __expf(C[sub][2] - m);
            const float e3 = __expf(C[sub][3] - m);
            s0 += e0 + e1;
            s1 += e2 + e3;
            pk[sub][0] = cvtpk(e0, e1);
            pk[sub][1] = cvtpk(e2, e3);
        }
        lp += s0 + s1;

        // ---- build PV A-frags (P[q=c][kv half*32 + g*8 + j]) and PV ----
#pragma unroll
        for (int half = 0; half < 2; ++half) {
            const int x0 = (int)pk[2 * half][0], x1 = (int)pk[2 * half][1];
            const int x2 = (int)pk[2 * half + 1][0], x3 = (int)pk[2 * half + 1][1];
            const int sA = ((g & 1) * 2) * 16 + c;
            const int sB = sA + 16;
            const uint u0 = (uint)__shfl(x0, sA), u1 = (uint)__shfl(x1, sA);
            const uint u2 = (uint)__shfl(x2, sA), u3 = (uint)__shfl(x3, sA);
            const uint v0 = (uint)__shfl(x0, sB), v1 = (uint)__shfl(x1, sB);
            const uint v2 = (uint)__shfl(x2, sB), v3 = (uint)__shfl(x3, sB);
            const bool hb = (g >> 1) != 0;
            uint4 fu;
            fu.x = hb ? u2 : u0;
            fu.y = hb ? u3 : u1;
            fu.z = hb ? v2 : v0;
            fu.w = hb ? v3 : v1;
            const bf16x8 pa = *(const bf16x8*)&fu;
            __builtin_amdgcn_s_setprio(1);
#pragma unroll
            for (int nf = 0; nf < 4; ++nf) {
                const bf16x8 vf =
                    *(const bf16x8*)&Vt[cur][swz(nf * 16 + c, half * 4 + g)];
                acc[nf] = MFMA16(pa, vf, acc[nf]);
            }
            __builtin_amdgcn_s_setprio(0);
        }

        __syncthreads();   // reads of buf[cur] done; staged writes drained
    }

    // ---- epilogue: reduce lp across g-groups, redistribute, store ----
    float lv = lp;
    lv += __shfl_xor(lv, 16);
    lv += __shfl_xor(lv, 32);
#pragma unroll
    for (int r = 0; r < 4; ++r) {
        const float inv = 1.0f / __shfl(lv, g * 4 + r);
        const int qs = q0 + g * 4 + r;
        float* dst = &Aw[((size_t)b * Sn + qs) * Dn + h * DHn + c];
        dst[0]  = acc[0][r] * inv;
        dst[16] = acc[1][r] * inv;
        dst[32] = acc[2][r] * inv;
        dst[48] = acc[3][r] * inv;
    }
}

// ---------------------------------------------------------------------------
// LayerNorm over D=1024 per (b,s) row; f32 output.
// ---------------------------------------------------------------------------
__global__ __launch_bounds__(256) void ln_kernel(
    const float* __restrict__ Aw, const float* __restrict__ gamma,
    const float* __restrict__ beta, float* __restrict__ out)
{
    const int row = blockIdx.x;
    const int tid = threadIdx.x;
    const int d0 = tid * 4;
    const float4 x = *(const float4*)&Aw[(size_t)row * Dn + d0];
    float sum = x.x + x.y + x.z + x.w;
    float sq = x.x * x.x + x.y * x.y + x.z * x.z + x.w * x.w;
    for (int off = 32; off; off >>= 1) {
        sum += __shfl_xor(sum, off);
        sq += __shfl_xor(sq, off);
    }
    __shared__ float red[8];
    const int lane = tid & 63, wave = tid >> 6;
    if (lane == 0) { red[wave] = sum; red[wave + 4] = sq; }
    __syncthreads();
    if (tid == 0) {
        red[0] = red[0] + red[1] + red[2] + red[3];
        red[4] = red[4] + red[5] + red[6] + red[7];
    }
    __syncthreads();
    sum = red[0]; sq = red[4];
    const float mu = sum * (1.0f / Dn);
    const float var = sq * (1.0f / Dn) - mu * mu;
    const float rs = rsqrtf(var + 1e-5f);

    const float4 gv = *(const float4*)&gamma[d0];
    const float4 bv = *(const float4*)&beta[d0];
    float4 ov;
    ov.x = (x.x - mu) * rs * gv.x + bv.x;
    ov.y = (x.y - mu) * rs * gv.y + bv.y;
    ov.z = (x.z - mu) * rs * gv.z + bv.z;
    ov.w = (x.w - mu) * rs * gv.w + bv.w;
    *(float4*)&out[(size_t)row * Dn + d0] = ov;
}

extern "C" void kernel_launch(void* const* d_in, const int* in_sizes, int n_in,
                              void* d_out, int out_size, void* d_ws, size_t ws_size,
                              hipStream_t stream)
{
    const float* x_qk = (const float*)d_in[0];
    const float* x_v  = (const float*)d_in[1];
    const float* W_qk = (const float*)d_in[2];
    const float* b_qk = (const float*)d_in[3];
    const float* W_v  = (const float*)d_in[4];
    const float* b_v  = (const float*)d_in[5];
    const float* g    = (const float*)d_in[6];
    const float* be   = (const float*)d_in[7];

    char* ws = (char*)d_ws;
    ushort* Qw    = (ushort*)(ws);                  //  8 MB bf16 (b,h,s,dh)
    ushort* Kw    = (ushort*)(ws + (8u  << 20));    //  8 MB bf16 (b,h,s,dh)
    ushort* Vtw   = (ushort*)(ws + (16u << 20));    //  8 MB bf16 (b,h,dh,s)
    float*  Aw    = (float*) (ws + (24u << 20));    // 16 MB f32  (b,s,D)
    ushort* xqkB  = (ushort*)(ws + (40u << 20));    //  8 MB bf16 [M][K]
    ushort* xvB   = (ushort*)(ws + (48u << 20));    //  8 MB bf16 [M][K]
    ushort* WqkT  = (ushort*)(ws + (56u << 20));    //  4 MB bf16 [2048][1024]
    ushort* WvT   = (ushort*)(ws + (60u << 20));    //  2 MB bf16 [1024][1024]
    float*  ctab  = (float*) (ws + (62u << 20));    // 256 KB
    float*  stab  = (float*) (ws + (62u << 20) + (256u << 10));

    rope_tab<<<256, 256, 0, stream>>>(ctab, stab);
    cvt_bf16<<<2048, 256, 0, stream>>>(x_qk, xqkB);
    cvt_bf16<<<2048, 256, 0, stream>>>(x_v, xvB);
    transpose_bf16<<<dim3(64, 32), dim3(32, 8), 0, stream>>>(W_qk, WqkT, Kd, 2048);
    transpose_bf16<<<dim3(32, 32), dim3(32, 8), 0, stream>>>(W_v, WvT, Kd, 1024);

    gemm_mfma<0><<<dim3(16, 32), 256, 0, stream>>>(
        xqkB, WqkT, b_qk, ctab, stab, Qw, Kw);
    gemm_mfma<1><<<dim3(8, 32), 256, 0, stream>>>(
        xvB, WvT, b_v, ctab, stab, Vtw, nullptr);

    attn_mfma<<<dim3(32, 32), 256, 0, stream>>>(Qw, Kw, Vtw, Aw);
    ln_kernel<<<Bn * Sn, 256, 0, stream>>>(Aw, g, be, (float*)d_out);
}